// Round 1
// baseline (81.997 us; speedup 1.0000x reference)
//
#include <hip/hip_runtime.h>
#include <math.h>

#define NB 16      // batches
#define NN 1024    // visual tokens
#define ND 768     // feature dim
#define NT 256     // text tokens
#define NSEL 16    // selections
#define NC 64      // greedy candidate set (global top-64 by initial di2s)

typedef __attribute__((ext_vector_type(8))) short short8;
typedef __attribute__((ext_vector_type(4))) float f32x4;
typedef __attribute__((ext_vector_type(8))) unsigned short ushort8v;
typedef unsigned long long u64;

// ---- device scratch (every read dominated by a same-launch write) ----
__device__ __align__(16) float g_invv[NB*NN];
__device__ __align__(16) float g_diagv[NB*NN];
__device__ __align__(16) float g_mrawp[NB*NN*2];  // per-128-text-half rowmax
// fragment-order pre-split text: unit(b,th,s,h,ct,lane) of 16B (8 bf16); s = 32-k step
__device__ __align__(16) ushort8v g_tf[NB*2*24*2*8*64];

__device__ __forceinline__ unsigned short f2bf(float x) {
    unsigned u = __float_as_uint(x);
    return (unsigned short)((u + 0x7FFFu + ((u >> 16) & 1u)) >> 16);
}
__device__ __forceinline__ float bf2f(unsigned short h) {
    return __uint_as_float(((unsigned)h) << 16);
}
__device__ __forceinline__ size_t tfidx(int b, int th, int s, int h, int ct, int lane) {
    return ((((size_t)(b*2 + th)*24 + s)*2 + h)*8 + ct)*64 + lane;
}

// ---------------- K1: text norms + bf16 hi/lo split -> FRAGMENT-ORDER global ----------------
__global__ __launch_bounds__(256) void ktxt(const float* __restrict__ txt) {
    int gw = (blockIdx.x * 256 + threadIdx.x) >> 6;   // row 0..NB*NT-1
    int l  = threadIdx.x & 63;
    int b  = gw >> 8, r = gw & 255;
    int th = r >> 7, ct = (r >> 4) & 7, rlo = r & 15;
    const float* row = txt + (size_t)gw * ND;

    float4 x0 = *(const float4*)(row + 8*l);
    float4 y0 = *(const float4*)(row + 8*l + 4);
    float4 x1 = {0,0,0,0}, y1 = {0,0,0,0};
    bool two = (l < 32);
    if (two) {
        x1 = *(const float4*)(row + 512 + 8*l);
        y1 = *(const float4*)(row + 512 + 8*l + 4);
    }
    float s = x0.x*x0.x + x0.y*x0.y + x0.z*x0.z + x0.w*x0.w
            + y0.x*y0.x + y0.y*y0.y + y0.z*y0.z + y0.w*y0.w;
    if (two) s += x1.x*x1.x + x1.y*x1.y + x1.z*x1.z + x1.w*x1.w
                + y1.x*y1.x + y1.y*y1.y + y1.z*y1.z + y1.w*y1.w;
    #pragma unroll
    for (int off = 32; off; off >>= 1) s += __shfl_xor(s, off);
    float inv = 1.0f / (sqrtf(s) + 1e-6f);

    int kslot = l & 3;
    int lane  = kslot*16 + rlo;
    {   // chunk 0: e0 = 8l, s-step = l>>2
        int st = l >> 2;
        float a[8] = {x0.x, x0.y, x0.z, x0.w, y0.x, y0.y, y0.z, y0.w};
        ushort8v hh, ll;
        #pragma unroll
        for (int j = 0; j < 8; j++) {
            float v = a[j] * inv;
            hh[j] = f2bf(v);
            ll[j] = f2bf(v - bf2f(hh[j]));
        }
        g_tf[tfidx(b, th, st, 0, ct, lane)] = hh;
        g_tf[tfidx(b, th, st, 1, ct, lane)] = ll;
    }
    if (two) {  // chunk 1: e0 = 512+8l, s-step = 16 + (l>>2)
        int st = 16 + (l >> 2);
        float a[8] = {x1.x, x1.y, x1.z, x1.w, y1.x, y1.y, y1.z, y1.w};
        ushort8v hh, ll;
        #pragma unroll
        for (int j = 0; j < 8; j++) {
            float v = a[j] * inv;
            hh[j] = f2bf(v);
            ll[j] = f2bf(v - bf2f(hh[j]));
        }
        g_tf[tfidx(b, th, st, 0, ct, lane)] = hh;
        g_tf[tfidx(b, th, st, 1, ct, lane)] = ll;
    }
}

// ---------------- K2 v2: barrier-free MFMA relevance GEMM, B direct from L2/L1 ----------------
// Structural change vs r20 (LDS-staged): krel was LDS-pipe-bound (4 waves re-read the same
// 16KB B tile from LDS each step: ~1540 cyc/CU/step vs ~310 cyc MFMA/SIMD) + per-step
// full-block barrier drain. v2: 32 rows/wave (2 M-frags -> half the B reads per row), B
// fragments loaded straight from fragment-ordered g_tf (coalesced 1KB wave-loads; the 4
// waves of a block share one 16KB step-tile -> L1-resident, L2 sees ~16KB/step/CU), zero
// __syncthreads in the loop; raw s_barrier rendezvous only, to keep the block L1-lockstep.
// MFMA order per output element unchanged -> bit-identical relevance/invv/diag.
// Grid: 256 blocks = 16b x 8mt x 2th, 1 block/CU. XCD swizzle: bids == x (mod 8) form
// lids x*32..x*32+31 = 2 full batches (all mt, both th) -> 1.5MB of g_tf per XCD L2,
// th-pairs co-XCD so the duplicate A read hits L2.
__global__ __launch_bounds__(256, 1) void krel(const float* __restrict__ vis) {
    int bid = blockIdx.x;
    int lid = (bid & 7) * 32 + (bid >> 3);   // XCD-grouped logical id (bijective, 256 = 8x32)
    int b   = lid >> 4;
    int r   = lid & 15;
    int mt  = r >> 1;
    int th  = r & 1;
    int t   = threadIdx.x;
    int w   = t >> 6, l = t & 63;

    f32x4 acc0[8], acc1[8];
    #pragma unroll
    for (int ct = 0; ct < 8; ct++) {
        acc0[ct] = (f32x4){0.f, 0.f, 0.f, 0.f};
        acc1[ct] = (f32x4){0.f, 0.f, 0.f, 0.f};
    }

    int base = mt*128 + w*32;                 // first of this wave's 32 rows
    // A fragments: frag m covers rows base+m*16+(l&15), k-slot (l>>4)*8
    const float* Ap0 = vis + ((size_t)(b*NN + base + (l & 15)))*ND + (l >> 4)*8;
    const float* Ap1 = Ap0 + (size_t)16*ND;

    // B fragment base for this (b,th), this lane
    const ushort8v* Bb = g_tf + (size_t)(b*2 + th)*(24*2*8*64) + l;

    // prologue: A regs for step 0
    float4 a0x = *(const float4*)(Ap0);
    float4 a0y = *(const float4*)(Ap0 + 4);
    float4 a1x = *(const float4*)(Ap1);
    float4 a1y = *(const float4*)(Ap1 + 4);
    float ss0 = 0.f, ss1 = 0.f;

    #define CONV8(AX, AY, AH, AL, SS)                                          \
        {                                                                      \
            float av_[8] = {AX.x, AX.y, AX.z, AX.w, AY.x, AY.y, AY.z, AY.w};   \
            ushort8v hh_, ll_;                                                 \
            _Pragma("unroll")                                                  \
            for (int j = 0; j < 8; j++) {                                      \
                hh_[j] = f2bf(av_[j]);                                         \
                ll_[j] = f2bf(av_[j] - bf2f(hh_[j]));                          \
                SS = fmaf(av_[j], av_[j], SS);                                 \
            }                                                                  \
            AH = *(short8*)&hh_;                                               \
            AL = *(short8*)&ll_;                                               \
        }

    #define MM(ACC, AA, BB)                                                    \
        _Pragma("unroll")                                                      \
        for (int ct = 0; ct < 8; ct++)                                         \
            ACC[ct] = __builtin_amdgcn_mfma_f32_16x16x32_bf16(                 \
                AA, *(short8*)&BB[ct], ACC[ct], 0, 0, 0);

    for (int s = 0; s < 24; s++) {
        // B loads for this step: 16 coalesced dwordx4 (1KB/wave-load) from L1/L2
        const ushort8v* Bs = Bb + (size_t)s*(2*8*64);
        ushort8v bh[8], blv[8];
        #pragma unroll
        for (int ct = 0; ct < 8; ct++) {
            bh[ct]  = Bs[ct*64];            // h=0 (hi)
            blv[ct] = Bs[(8 + ct)*64];      // h=1 (lo)
        }
        // A prefetch for step s+1 (in flight across this step's conv+MFMA)
        float4 n0x, n0y, n1x, n1y;
        if (s < 23) {
            int k1 = (s + 1) * 32;
            n0x = *(const float4*)(Ap0 + k1);
            n0y = *(const float4*)(Ap0 + k1 + 4);
            n1x = *(const float4*)(Ap1 + k1);
            n1y = *(const float4*)(Ap1 + k1 + 4);
        }
        // convert A regs -> hi/lo fragments + sumsq (VALU hides the B-load latency)
        short8 ah0, al0, ah1, al1;
        CONV8(a0x, a0y, ah0, al0, ss0);
        CONV8(a1x, a1y, ah1, al1, ss1);
        // MFMA: per (m,ct) the pass order is hh, lh, hl, ll -> bit-identical to r20
        MM(acc0, ah0, bh)  MM(acc0, al0, bh)  MM(acc0, ah0, blv)  MM(acc0, al0, blv)
        MM(acc1, ah1, bh)  MM(acc1, al1, bh)  MM(acc1, ah1, blv)  MM(acc1, al1, blv)
        if (s < 23) { a0x = n0x; a0y = n0y; a1x = n1x; a1y = n1y; }
        // exec-only rendezvous (no waitcnt, no LDS): keeps the 4 waves sharing the
        // same step-tile in L1; not required for correctness
        __builtin_amdgcn_s_barrier();
    }
    #undef MM
    #undef CONV8

    // rowmax over this half's 128 cols (exact; kfinal maxes the 2 halves) + invv/diag
    #define EPI(ACC, MOFF, SS)                                                 \
        {                                                                      \
            _Pragma("unroll")                                                  \
            for (int rr = 0; rr < 4; rr++) {                                   \
                float mx_ = ACC[0][rr];                                        \
                _Pragma("unroll")                                              \
                for (int ct = 1; ct < 8; ct++) mx_ = fmaxf(mx_, ACC[ct][rr]);  \
                _Pragma("unroll")                                              \
                for (int off = 1; off <= 8; off <<= 1)                         \
                    mx_ = fmaxf(mx_, __shfl_xor(mx_, off));                    \
                if ((l & 15) == 0)                                             \
                    g_mrawp[(size_t)(b*NN + base + (MOFF) + (l >> 4)*4 + rr)*2 + th] = mx_; \
            }                                                                  \
            float sst_ = SS;                                                   \
            sst_ += __shfl_xor(sst_, 16);                                      \
            sst_ += __shfl_xor(sst_, 32);                                      \
            if (th == 0 && l < 16) {                                           \
                int row_ = base + (MOFF) + l;                                  \
                float nrm_ = sqrtf(sst_);                                      \
                float inv_ = 1.0f / (nrm_ + 1e-6f);                            \
                g_invv[b*NN + row_] = inv_;                                    \
                float dd_ = nrm_ * inv_;                                       \
                g_diagv[b*NN + row_] = dd_ * dd_;                              \
            }                                                                  \
        }
    EPI(acc0, 0,  ss0)
    EPI(acc1, 16, ss1)
    #undef EPI
}

// ---------------- K3: prep + reg-sort top-64 + MFMA Gram + single-wave greedy + gather ----------------
__global__ __launch_bounds__(1024) void kfinal(const float* __restrict__ vis,
                                               float* __restrict__ out) {
    int b = blockIdx.x;
    int t = threadIdx.x;
    int w = t >> 6, l = t & 63;

    __shared__ u64   s_key[NN];
    __shared__ float s_reln[NN];
    __shared__ __align__(16) unsigned short Chi[NC][392], Clo[NC][392];  // K-chunk 384 + pad
    __shared__ float s_S[NC*65];
    __shared__ int   s_sel[NSEL], s_srt[NSEL];
    __shared__ float s_mn[16], s_mx[16], s_b2[2];

    // ---- prep: relevance minmax-normalize, di2s0, key (1 elem/thread) ----
    float m0 = g_mrawp[(size_t)(b*NN + t)*2 + 0];
    float m1 = g_mrawp[(size_t)(b*NN + t)*2 + 1];
    float iv = g_invv[b*NN + t], dd = g_diagv[b*NN + t];
    float rr = fmaxf(m0, m1) * iv;
    float lmin = rr, lmax = rr;
    #pragma unroll
    for (int off = 32; off; off >>= 1) {
        lmin = fminf(lmin, __shfl_xor(lmin, off));
        lmax = fmaxf(lmax, __shfl_xor(lmax, off));
    }
    if (l == 0) { s_mn[w] = lmin; s_mx[w] = lmax; }
    __syncthreads();
    if (t == 0) {
        float mn = s_mn[0], mx = s_mx[0];
        #pragma unroll
        for (int q = 1; q < 16; q++) { mn = fminf(mn, s_mn[q]); mx = fmaxf(mx, s_mx[q]); }
        s_b2[0] = mn; s_b2[1] = mx;
    }
    __syncthreads();
    float mn = s_b2[0], mx = s_b2[1];
    float den = mx - mn + 1e-6f;
    float rn = (rr - mn + 1e-6f) / den;
    float d0 = rn * rn * dd;
    s_reln[t] = rn;
    u64 kreg = ((u64)(~__float_as_uint(d0)) << 10) | (unsigned)t;

    // ---- per-wave in-register bitonic sort (ascending key = descending d0) ----
    #pragma unroll
    for (int k = 2; k <= 64; k <<= 1) {
        #pragma unroll
        for (int j = k >> 1; j > 0; j >>= 1) {
            u64 part = __shfl_xor(kreg, j);
            bool takeMin = ((l & k) == 0) == ((l & j) == 0);
            kreg = takeMin ? (kreg < part ? kreg : part) : (kreg < part ? part : kreg);
        }
    }
    // ---- symmetric tournament merge: 4 rounds, every wave ends with global top-64 ----
    #pragma unroll
    for (int rnd = 0; rnd < 4; rnd++) {
        int dstp = 8 >> rnd;
        s_key[w*64 + l] = kreg;
        __syncthreads();
        u64 other = s_key[(w ^ dstp)*64 + (63 - l)];
        u64 m = (kreg < other) ? kreg : other;     // 64 smallest of union (bitonic)
        #pragma unroll
        for (int j = 32; j > 0; j >>= 1) {         // ascending clean
            u64 part = __shfl_xor(m, j);
            bool takeMin = ((l & j) == 0);
            m = takeMin ? (m < part ? m : part) : (m < part ? part : m);
        }
        kreg = m;
        __syncthreads();
    }

    // lane l of every wave: l-th best candidate
    int   gid = (int)(kreg & 1023u);
    float d0v = __uint_as_float(~(unsigned)(kreg >> 10));

    // ---- Gram S = vn_c . vn_c^T via bf16x4 MFMA, 2 chunks of K=384 ----
    f32x4 acc = (f32x4){0.f, 0.f, 0.f, 0.f};
    int ar0 = (w >> 2) * 16, bc0 = (w & 3) * 16;
    int cr  = (w << 2) + (l >> 4);                 // candidate row this thread stages
    int sgid = __shfl(gid, cr);
    float sc = g_invv[b*NN + sgid];
    const float* srcrow = vis + (size_t)(b*NN + sgid)*ND + (l & 15)*24;

    for (int c = 0; c < 2; c++) {
        __syncthreads();
        int kb = (l & 15) * 24;
        #pragma unroll
        for (int q = 0; q < 3; q++) {
            float4 x = *(const float4*)(srcrow + c*384 + q*8);
            float4 y = *(const float4*)(srcrow + c*384 + q*8 + 4);
            float av[8] = {x.x, x.y, x.z, x.w, y.x, y.y, y.z, y.w};
            ushort8v hh, ll;
            #pragma unroll
            for (int j = 0; j < 8; j++) {
                float vv = av[j] * sc;
                hh[j] = f2bf(vv);
                ll[j] = f2bf(vv - bf2f(hh[j]));
            }
            *(ushort8v*)&Chi[cr][kb + q*8] = hh;
            *(ushort8v*)&Clo[cr][kb + q*8] = ll;
        }
        __syncthreads();
        #pragma unroll
        for (int ks = 0; ks < 12; ks++) {
            int ko = ks*32 + (l >> 4)*8;
            short8 ah = *(const short8*)&Chi[ar0 + (l & 15)][ko];
            short8 al = *(const short8*)&Clo[ar0 + (l & 15)][ko];
            short8 bh = *(const short8*)&Chi[bc0 + (l & 15)][ko];
            short8 bl = *(const short8*)&Clo[bc0 + (l & 15)][ko];
            acc = __builtin_amdgcn_mfma_f32_16x16x32_bf16(ah, bh, acc, 0, 0, 0);
            acc = __builtin_amdgcn_mfma_f32_16x16x32_bf16(al, bh, acc, 0, 0, 0);
            acc = __builtin_amdgcn_mfma_f32_16x16x32_bf16(ah, bl, acc, 0, 0, 0);
            acc = __builtin_amdgcn_mfma_f32_16x16x32_bf16(al, bl, acc, 0, 0, 0);
        }
    }
    #pragma unroll
    for (int r = 0; r < 4; r++)
        s_S[(ar0 + (l >> 4)*4 + r)*65 + bc0 + (l & 15)] = acc[r];
    __syncthreads();

    // ---- single-wave greedy: lane = candidate, zero barriers, all state in registers ----
    if (w == 0) {
        float di  = d0v;
        int   gd  = gid;
        float rel = s_reln[gid];
        float ownc[NSEL];
        #pragma unroll
        for (int i = 0; i < NSEL; i++) {
            float vq = fmaxf(di, 1e-12f);
            int   gq = gd;
            int   cq = l;
            #pragma unroll
            for (int off = 32; off; off >>= 1) {
                float vo = __shfl_xor(vq, off);
                int   go = __shfl_xor(gq, off);
                int   co = __shfl_xor(cq, off);
                if (vo > vq || (vo == vq && go < gq)) { vq = vo; gq = go; cq = co; }
            }
            float dj   = __shfl(di, cq);
            float relj = __shfl(rel, cq);
            float denom = sqrtf(fmaxf(dj, 1e-12f)) + 1e-8f;
            if (l == 0) s_sel[i] = gq;

            float cov = 0.f;
            #pragma unroll
            for (int q = 0; q < i; q++)
                cov = fmaf(ownc[q], __shfl(ownc[q], cq), cov);

            float sim = s_S[l*65 + cq];
            float kj  = rel * relj * sim;
            float eis = (kj - cov) / denom;
            ownc[i] = eis;
            di = di - eis * eis;
            if (l == cq) di = -__builtin_inff();
        }
    }
    __syncthreads();

    // ---- sort selected indices; wave w gathers output row w ----
    if (t == 0) {
        int vv[16];
        #pragma unroll
        for (int q = 0; q < 16; q++) vv[q] = s_sel[q];
        for (int a = 1; a < 16; a++) {
            int key = vv[a]; int p2 = a - 1;
            while (p2 >= 0 && vv[p2] > key) { vv[p2+1] = vv[p2]; p2--; }
            vv[p2+1] = key;
        }
        #pragma unroll
        for (int q = 0; q < 16; q++) s_srt[q] = vv[q];
    }
    __syncthreads();
    {
        int idx = s_srt[w];
        const float* src = vis + (size_t)(b*NN + idx)*ND + l*12;
        float*       dst = out + (size_t)(b*NSEL + w)*ND + l*12;
        float4 x = *(const float4*)(src);
        float4 y = *(const float4*)(src + 4);
        float4 z = *(const float4*)(src + 8);
        *(float4*)(dst)     = x;
        *(float4*)(dst + 4) = y;
        *(float4*)(dst + 8) = z;
    }
}

extern "C" void kernel_launch(void* const* d_in, const int* in_sizes, int n_in,
                              void* d_out, int out_size, void* d_ws, size_t ws_size,
                              hipStream_t stream) {
    (void)in_sizes; (void)n_in; (void)d_ws; (void)ws_size; (void)out_size;
    const float* vis = (const float*)d_in[0];
    const float* txt = (const float*)d_in[1];
    float* out = (float*)d_out;

    ktxt  <<<dim3((NB*NT)/4), dim3(256),  0, stream>>>(txt);
    krel  <<<dim3(256),       dim3(256),  0, stream>>>(vis);
    kfinal<<<dim3(NB),        dim3(1024), 0, stream>>>(vis, out);
}